// Round 1
// baseline (431.957 us; speedup 1.0000x reference)
//
#include <hip/hip_runtime.h>
#include <math.h>

#define B_ 8
#define N_ 4096
#define C_ 8
#define T_ 256
#define NCHUNK 64
#define CHUNKS (N_ / NCHUNK)  // 64 chunks per batch

// ---------------------------------------------------------------------------
// Pass 1: single streaming pass over x (268 MB).
// Computes per-block partials of:
//   x_u1[b,t,c] = sum_n x[b,n,c,t] * u1[n]
//   R2[b,c,t]   = sum_n u2[c,n] * rhs[b,n,t],  rhs[b,n,t] = sum_c x[b,n,c,t]*u3[c]
// Block = 256 threads = 4 waves; each wave processes one n per round
// (thread owns 4 consecutive t via float4 loads -> perfectly coalesced).
// NCHUNK=64: 512 blocks (2/CU, 8 waves/CU) halves partial traffic vs 32.
// ---------------------------------------------------------------------------
__global__ __launch_bounds__(256) void pass1(
    const float* __restrict__ x, const float* __restrict__ u1,
    const float* __restrict__ u2, const float* __restrict__ u3,
    float* __restrict__ p1, float* __restrict__ p2) {
  const int blk = blockIdx.x;
  const int b = blk / CHUNKS;
  const int chunk = blk % CHUNKS;
  const int n0 = chunk * NCHUNK;
  const int tid = threadIdx.x;
  const int sub = tid >> 6;   // wave id within block (0..3)
  const int lane = tid & 63;
  const int t0 = lane << 2;   // 4 t-values per thread

  float u3r[C_];
#pragma unroll
  for (int c = 0; c < C_; ++c) u3r[c] = u3[c];

  float a1[C_][4];  // x_u1 partials (this thread's 4 t's, all c)
  float a2[C_][4];  // R2 partials
#pragma unroll
  for (int c = 0; c < C_; ++c)
#pragma unroll
    for (int q = 0; q < 4; ++q) { a1[c][q] = 0.f; a2[c][q] = 0.f; }

  for (int r = 0; r < NCHUNK / 4; ++r) {
    const int n = n0 + r * 4 + sub;  // each wave: its own n
    const float* xp = x + ((size_t)(b * N_ + n) * C_) * T_ + t0;
    const float w1 = u1[n];
    float rh0 = 0.f, rh1 = 0.f, rh2 = 0.f, rh3 = 0.f;
#pragma unroll
    for (int c = 0; c < C_; ++c) {
      const float4 xv = *(const float4*)(xp + c * T_);
      rh0 = fmaf(u3r[c], xv.x, rh0);
      rh1 = fmaf(u3r[c], xv.y, rh1);
      rh2 = fmaf(u3r[c], xv.z, rh2);
      rh3 = fmaf(u3r[c], xv.w, rh3);
      a1[c][0] = fmaf(w1, xv.x, a1[c][0]);
      a1[c][1] = fmaf(w1, xv.y, a1[c][1]);
      a1[c][2] = fmaf(w1, xv.z, a1[c][2]);
      a1[c][3] = fmaf(w1, xv.w, a1[c][3]);
    }
#pragma unroll
    for (int c = 0; c < C_; ++c) {
      const float w2 = u2[c * N_ + n];
      a2[c][0] = fmaf(w2, rh0, a2[c][0]);
      a2[c][1] = fmaf(w2, rh1, a2[c][1]);
      a2[c][2] = fmaf(w2, rh2, a2[c][2]);
      a2[c][3] = fmaf(w2, rh3, a2[c][3]);
    }
  }

  // cross-wave (sub) reduction via LDS, then one partial record per block
  __shared__ float red[4][C_ * T_];  // 32 KB
  const size_t pbase = (size_t)blk * (C_ * T_);

#pragma unroll
  for (int c = 0; c < C_; ++c)
#pragma unroll
    for (int q = 0; q < 4; ++q) red[sub][c * T_ + t0 + q] = a1[c][q];
  __syncthreads();
  for (int e = tid; e < C_ * T_; e += 256)
    p1[pbase + e] = red[0][e] + red[1][e] + red[2][e] + red[3][e];
  __syncthreads();

#pragma unroll
  for (int c = 0; c < C_; ++c)
#pragma unroll
    for (int q = 0; q < 4; ++q) red[sub][c * T_ + t0 + q] = a2[c][q];
  __syncthreads();
  for (int e = tid; e < C_ * T_; e += 256)
    p2[pbase + e] = red[0][e] + red[1][e] + red[2][e] + red[3][e];
}

// ---------------------------------------------------------------------------
// Pass 2: reduce 64 chunk-partials per batch into x_u1[b][c][t], R2[b][c][t].
// Split over 4 k-groups with atomicAdd (outputs memset to 0 first).
// grid = 2 arrays * 64 groups * 4 splits = 512 blocks
// ---------------------------------------------------------------------------
__global__ __launch_bounds__(256) void reduce2(
    const float* __restrict__ p1, const float* __restrict__ p2,
    float* __restrict__ x_u1, float* __restrict__ r2) {
  const int arr = blockIdx.x >> 8;
  const int g = (blockIdx.x & 255) >> 2;
  const int s = blockIdx.x & 3;
  const int idx = g * 256 + threadIdx.x;  // 0..16383 = b*2048 + (c*T+t)
  const int b = idx >> 11;
  const int e = idx & 2047;
  const float* src = arr ? p2 : p1;
  float* dst = arr ? r2 : x_u1;
  const float* q = src + (size_t)(b * CHUNKS + s * 16) * 2048 + e;
  float acc = 0.f;
#pragma unroll 8
  for (int k = 0; k < 16; ++k) acc += q[(size_t)k * 2048];
  atomicAdd(dst + idx, acc);
}

// ---------------------------------------------------------------------------
// Pass 3 (fused prodsig + esoftmax):
//   E[b,i,j] = sum_k v[i,k] * sigmoid( sum_c x_u1[b,k,c]*R2[b,c,j] + bias[k,j] )
// then stable softmax over j. The sigmoid argument is recomputed per block
// (x_u1/r2 are 16 KB per batch, L2/scalar-cache resident; 8 FMA per element),
// eliminating the S intermediate (2 MB W + 8 MB R) and one dispatch.
// Block handles 8 rows (i) for one b; thread owns column j.
// grid = B * 32 = 256 blocks
// ---------------------------------------------------------------------------
__global__ __launch_bounds__(256) void pse(
    const float* __restrict__ x_u1, const float* __restrict__ r2,
    const float* __restrict__ bias, const float* __restrict__ v,
    float* __restrict__ out) {
  __shared__ float vlds[8][T_];  // 8 KB: v rows for this tile
  __shared__ float elds[8][T_];  // 8 KB: E tile
  __shared__ float rmax[8], rinv[8];
  const int b = blockIdx.x >> 5;
  const int i0 = (blockIdx.x & 31) << 3;
  const int j = threadIdx.x;

#pragma unroll
  for (int r = 0; r < 8; ++r) vlds[r][j] = v[(i0 + r) * T_ + j];
  __syncthreads();

  // this thread's column of R2 (held in regs for the whole k-loop)
  float r2c[C_];
#pragma unroll
  for (int c = 0; c < C_; ++c) r2c[c] = r2[b * 2048 + c * T_ + j];
  const float* xu = x_u1 + b * 2048;  // [c][t] layout, uniform -> scalar loads

  float acc[8] = {0.f, 0.f, 0.f, 0.f, 0.f, 0.f, 0.f, 0.f};
#pragma unroll 4
  for (int k = 0; k < T_; ++k) {
    float p = bias[k * T_ + j];
#pragma unroll
    for (int c = 0; c < C_; ++c) p = fmaf(xu[c * T_ + k], r2c[c], p);
    const float sg = 1.f / (1.f + __expf(-p));
#pragma unroll
    for (int r = 0; r < 8; ++r) acc[r] = fmaf(vlds[r][k], sg, acc[r]);
  }

#pragma unroll
  for (int r = 0; r < 8; ++r) elds[r][j] = acc[r];
  __syncthreads();

  const int wave = j >> 6, lane = j & 63;
  for (int r = wave; r < 8; r += 4) {
    float m = -INFINITY;
#pragma unroll
    for (int q = 0; q < 4; ++q) m = fmaxf(m, elds[r][lane + q * 64]);
#pragma unroll
    for (int off = 32; off > 0; off >>= 1) m = fmaxf(m, __shfl_xor(m, off, 64));
    float sm = 0.f;
#pragma unroll
    for (int q = 0; q < 4; ++q) sm += expf(elds[r][lane + q * 64] - m);
#pragma unroll
    for (int off = 32; off > 0; off >>= 1) sm += __shfl_xor(sm, off, 64);
    if (lane == 0) { rmax[r] = m; rinv[r] = 1.f / sm; }
  }
  __syncthreads();

  float* ob = out + ((size_t)b * T_ + i0) * T_;
#pragma unroll
  for (int r = 0; r < 8; ++r)
    ob[r * T_ + j] = expf(elds[r][j] - rmax[r]) * rinv[r];
}

// ---------------------------------------------------------------------------
extern "C" void kernel_launch(void* const* d_in, const int* in_sizes, int n_in,
                              void* d_out, int out_size, void* d_ws, size_t ws_size,
                              hipStream_t stream) {
  const float* x    = (const float*)d_in[0];
  const float* u1   = (const float*)d_in[1];
  const float* u2   = (const float*)d_in[2];
  const float* u3   = (const float*)d_in[3];
  const float* bias = (const float*)d_in[4];
  const float* v    = (const float*)d_in[5];
  float* out = (float*)d_out;

  char* ws = (char*)d_ws;
  float* p1   = (float*)(ws);                              // 4 MB (512 blocks * 2048 f)
  float* p2   = (float*)(ws + (4u << 20));                 // 4 MB
  float* x_u1 = (float*)(ws + (8u << 20));                 // 64 KB
  float* r2   = (float*)(ws + (8u << 20) + (64u << 10));   // 64 KB

  // zero the atomic-accumulated outputs (ws is poisoned each call)
  hipMemsetAsync(x_u1, 0, 128u << 10, stream);

  pass1<<<B_ * CHUNKS, 256, 0, stream>>>(x, u1, u2, u3, p1, p2);
  reduce2<<<512, 256, 0, stream>>>(p1, p2, x_u1, r2);
  pse<<<B_ * (T_ / 8), 256, 0, stream>>>(x_u1, r2, bias, v, out);
}

// Round 2
// 411.756 us; speedup vs baseline: 1.0491x; 1.0491x over previous
//
#include <hip/hip_runtime.h>
#include <math.h>

#define B_ 8
#define N_ 4096
#define C_ 8
#define T_ 256
#define NCHUNK 32
#define CHUNKS (N_ / NCHUNK)  // 128 chunks per batch

// ---------------------------------------------------------------------------
// Pass 1: single streaming pass over x (268 MB).
// Computes per-block partials of:
//   x_u1[b,t,c] = sum_n x[b,n,c,t] * u1[n]
//   R2[b,c,t]   = sum_n u2[c,n] * rhs[b,n,t],  rhs[b,n,t] = sum_c x[b,n,c,t]*u3[c]
// Block = 256 threads = 4 waves; each wave processes one n per round
// (thread owns 4 consecutive t via float4 loads -> perfectly coalesced).
// NCHUNK=32 / 1024 blocks (4/CU, 16 waves/CU): NCHUNK=64 regressed +46 us
// (round 1) — keep the 16-wave/CU occupancy for latency hiding.
// ---------------------------------------------------------------------------
__global__ __launch_bounds__(256) void pass1(
    const float* __restrict__ x, const float* __restrict__ u1,
    const float* __restrict__ u2, const float* __restrict__ u3,
    float* __restrict__ p1, float* __restrict__ p2) {
  const int blk = blockIdx.x;
  const int b = blk / CHUNKS;
  const int chunk = blk % CHUNKS;
  const int n0 = chunk * NCHUNK;
  const int tid = threadIdx.x;
  const int sub = tid >> 6;   // wave id within block (0..3)
  const int lane = tid & 63;
  const int t0 = lane << 2;   // 4 t-values per thread

  float u3r[C_];
#pragma unroll
  for (int c = 0; c < C_; ++c) u3r[c] = u3[c];

  float a1[C_][4];  // x_u1 partials (this thread's 4 t's, all c)
  float a2[C_][4];  // R2 partials
#pragma unroll
  for (int c = 0; c < C_; ++c)
#pragma unroll
    for (int q = 0; q < 4; ++q) { a1[c][q] = 0.f; a2[c][q] = 0.f; }

  for (int r = 0; r < NCHUNK / 4; ++r) {
    const int n = n0 + r * 4 + sub;  // each wave: its own n
    const float* xp = x + ((size_t)(b * N_ + n) * C_) * T_ + t0;
    const float w1 = u1[n];
    float rh0 = 0.f, rh1 = 0.f, rh2 = 0.f, rh3 = 0.f;
#pragma unroll
    for (int c = 0; c < C_; ++c) {
      const float4 xv = *(const float4*)(xp + c * T_);
      rh0 = fmaf(u3r[c], xv.x, rh0);
      rh1 = fmaf(u3r[c], xv.y, rh1);
      rh2 = fmaf(u3r[c], xv.z, rh2);
      rh3 = fmaf(u3r[c], xv.w, rh3);
      a1[c][0] = fmaf(w1, xv.x, a1[c][0]);
      a1[c][1] = fmaf(w1, xv.y, a1[c][1]);
      a1[c][2] = fmaf(w1, xv.z, a1[c][2]);
      a1[c][3] = fmaf(w1, xv.w, a1[c][3]);
    }
#pragma unroll
    for (int c = 0; c < C_; ++c) {
      const float w2 = u2[c * N_ + n];
      a2[c][0] = fmaf(w2, rh0, a2[c][0]);
      a2[c][1] = fmaf(w2, rh1, a2[c][1]);
      a2[c][2] = fmaf(w2, rh2, a2[c][2]);
      a2[c][3] = fmaf(w2, rh3, a2[c][3]);
    }
  }

  // cross-wave (sub) reduction via LDS, then one partial record per block
  __shared__ float red[4][C_ * T_];  // 32 KB
  const size_t pbase = (size_t)blk * (C_ * T_);

#pragma unroll
  for (int c = 0; c < C_; ++c)
#pragma unroll
    for (int q = 0; q < 4; ++q) red[sub][c * T_ + t0 + q] = a1[c][q];
  __syncthreads();
  for (int e = tid; e < C_ * T_; e += 256)
    p1[pbase + e] = red[0][e] + red[1][e] + red[2][e] + red[3][e];
  __syncthreads();

#pragma unroll
  for (int c = 0; c < C_; ++c)
#pragma unroll
    for (int q = 0; q < 4; ++q) red[sub][c * T_ + t0 + q] = a2[c][q];
  __syncthreads();
  for (int e = tid; e < C_ * T_; e += 256)
    p2[pbase + e] = red[0][e] + red[1][e] + red[2][e] + red[3][e];
}

// ---------------------------------------------------------------------------
// Pass 2: reduce 128 chunk-partials per batch into x_u1[b][c][t], R2[b][c][t].
// Split over 4 k-groups with atomicAdd (outputs memset to 0 first).
// grid = 2 arrays * 64 groups * 4 splits = 512 blocks
// ---------------------------------------------------------------------------
__global__ __launch_bounds__(256) void reduce2(
    const float* __restrict__ p1, const float* __restrict__ p2,
    float* __restrict__ x_u1, float* __restrict__ r2) {
  const int arr = blockIdx.x >> 8;
  const int g = (blockIdx.x & 255) >> 2;
  const int s = blockIdx.x & 3;
  const int idx = g * 256 + threadIdx.x;  // 0..16383 = b*2048 + (c*T+t)
  const int b = idx >> 11;
  const int e = idx & 2047;
  const float* src = arr ? p2 : p1;
  float* dst = arr ? r2 : x_u1;
  const float* q = src + (size_t)(b * CHUNKS + s * 32) * 2048 + e;
  float acc = 0.f;
#pragma unroll 8
  for (int k = 0; k < 32; ++k) acc += q[(size_t)k * 2048];
  atomicAdd(dst + idx, acc);
}

// ---------------------------------------------------------------------------
// Pass 3 (fused prodsig + esoftmax):
//   E[b,i,j] = sum_k v[i,k] * sigmoid( sum_c x_u1[b,k,c]*R2[b,c,j] + bias[k,j] )
// then stable softmax over j. The sigmoid argument is recomputed per block
// (x_u1/r2 are 16 KB per batch, L2-resident; 8 FMA per element),
// eliminating the S intermediate (2 MB W + 8 MB R) and one dispatch.
// Block handles 8 rows (i) for one b; thread owns column j.
// grid = B * 32 = 256 blocks
// ---------------------------------------------------------------------------
__global__ __launch_bounds__(256) void pse(
    const float* __restrict__ x_u1, const float* __restrict__ r2,
    const float* __restrict__ bias, const float* __restrict__ v,
    float* __restrict__ out) {
  __shared__ float vlds[8][T_];  // 8 KB: v rows for this tile
  __shared__ float elds[8][T_];  // 8 KB: E tile
  __shared__ float rmax[8], rinv[8];
  const int b = blockIdx.x >> 5;
  const int i0 = (blockIdx.x & 31) << 3;
  const int j = threadIdx.x;

#pragma unroll
  for (int r = 0; r < 8; ++r) vlds[r][j] = v[(i0 + r) * T_ + j];
  __syncthreads();

  // this thread's column of R2 (held in regs for the whole k-loop)
  float r2c[C_];
#pragma unroll
  for (int c = 0; c < C_; ++c) r2c[c] = r2[b * 2048 + c * T_ + j];
  const float* xu = x_u1 + b * 2048;  // [c][t] layout, uniform -> scalar loads

  float acc[8] = {0.f, 0.f, 0.f, 0.f, 0.f, 0.f, 0.f, 0.f};
#pragma unroll 4
  for (int k = 0; k < T_; ++k) {
    float p = bias[k * T_ + j];
#pragma unroll
    for (int c = 0; c < C_; ++c) p = fmaf(xu[c * T_ + k], r2c[c], p);
    const float sg = 1.f / (1.f + __expf(-p));
#pragma unroll
    for (int r = 0; r < 8; ++r) acc[r] = fmaf(vlds[r][k], sg, acc[r]);
  }

#pragma unroll
  for (int r = 0; r < 8; ++r) elds[r][j] = acc[r];
  __syncthreads();

  const int wave = j >> 6, lane = j & 63;
  for (int r = wave; r < 8; r += 4) {
    float m = -INFINITY;
#pragma unroll
    for (int q = 0; q < 4; ++q) m = fmaxf(m, elds[r][lane + q * 64]);
#pragma unroll
    for (int off = 32; off > 0; off >>= 1) m = fmaxf(m, __shfl_xor(m, off, 64));
    float sm = 0.f;
#pragma unroll
    for (int q = 0; q < 4; ++q) sm += expf(elds[r][lane + q * 64] - m);
#pragma unroll
    for (int off = 32; off > 0; off >>= 1) sm += __shfl_xor(sm, off, 64);
    if (lane == 0) { rmax[r] = m; rinv[r] = 1.f / sm; }
  }
  __syncthreads();

  float* ob = out + ((size_t)b * T_ + i0) * T_;
#pragma unroll
  for (int r = 0; r < 8; ++r)
    ob[r * T_ + j] = expf(elds[r][j] - rmax[r]) * rinv[r];
}

// ---------------------------------------------------------------------------
extern "C" void kernel_launch(void* const* d_in, const int* in_sizes, int n_in,
                              void* d_out, int out_size, void* d_ws, size_t ws_size,
                              hipStream_t stream) {
  const float* x    = (const float*)d_in[0];
  const float* u1   = (const float*)d_in[1];
  const float* u2   = (const float*)d_in[2];
  const float* u3   = (const float*)d_in[3];
  const float* bias = (const float*)d_in[4];
  const float* v    = (const float*)d_in[5];
  float* out = (float*)d_out;

  char* ws = (char*)d_ws;
  float* p1   = (float*)(ws);                              // 8 MB (1024 blocks * 2048 f)
  float* p2   = (float*)(ws + (8u << 20));                 // 8 MB
  float* x_u1 = (float*)(ws + (16u << 20));                // 64 KB
  float* r2   = (float*)(ws + (16u << 20) + (64u << 10));  // 64 KB

  // zero the atomic-accumulated outputs (ws is poisoned each call)
  hipMemsetAsync(x_u1, 0, 128u << 10, stream);

  pass1<<<B_ * CHUNKS, 256, 0, stream>>>(x, u1, u2, u3, p1, p2);
  reduce2<<<512, 256, 0, stream>>>(p1, p2, x_u1, r2);
  pse<<<B_ * (T_ / 8), 256, 0, stream>>>(x_u1, r2, bias, v, out);
}

// Round 3
// 382.802 us; speedup vs baseline: 1.1284x; 1.0756x over previous
//
#include <hip/hip_runtime.h>
#include <math.h>

#define B_ 8
#define N_ 4096
#define C_ 8
#define T_ 256
#define NCHUNK 32
#define CHUNKS (N_ / NCHUNK)  // 128 chunks per batch

// ---------------------------------------------------------------------------
// Pass 1: single streaming pass over x (268 MB).
// Computes per-block partials of:
//   x_u1[b,t,c] = sum_n x[b,n,c,t] * u1[n]
//   R2[b,c,t]   = sum_n u2[c,n] * rhs[b,n,t],  rhs[b,n,t] = sum_c x[b,n,c,t]*u3[c]
// Block = 256 threads = 4 waves; each wave processes one n per round
// (thread owns 4 consecutive t via float4 loads -> perfectly coalesced).
// NCHUNK=32 / 1024 blocks (4/CU, 16 waves/CU): NCHUNK=64 regressed (round 1).
// Epilogue: LDS cross-wave reduce, then atomicAdd directly into x_u1/r2 —
// removes the reduce2 dispatch and its 16 MB+16 MB partial round-trip.
// ---------------------------------------------------------------------------
__global__ __launch_bounds__(256) void pass1(
    const float* __restrict__ x, const float* __restrict__ u1,
    const float* __restrict__ u2, const float* __restrict__ u3,
    float* __restrict__ x_u1, float* __restrict__ r2) {
  const int blk = blockIdx.x;
  const int b = blk / CHUNKS;
  const int chunk = blk % CHUNKS;
  const int n0 = chunk * NCHUNK;
  const int tid = threadIdx.x;
  const int sub = tid >> 6;   // wave id within block (0..3)
  const int lane = tid & 63;
  const int t0 = lane << 2;   // 4 t-values per thread

  float u3r[C_];
#pragma unroll
  for (int c = 0; c < C_; ++c) u3r[c] = u3[c];

  float a1[C_][4];  // x_u1 partials (this thread's 4 t's, all c)
  float a2[C_][4];  // R2 partials
#pragma unroll
  for (int c = 0; c < C_; ++c)
#pragma unroll
    for (int q = 0; q < 4; ++q) { a1[c][q] = 0.f; a2[c][q] = 0.f; }

  for (int r = 0; r < NCHUNK / 4; ++r) {
    const int n = n0 + r * 4 + sub;  // each wave: its own n
    const float* xp = x + ((size_t)(b * N_ + n) * C_) * T_ + t0;
    const float w1 = u1[n];
    float rh0 = 0.f, rh1 = 0.f, rh2 = 0.f, rh3 = 0.f;
#pragma unroll
    for (int c = 0; c < C_; ++c) {
      const float4 xv = *(const float4*)(xp + c * T_);
      rh0 = fmaf(u3r[c], xv.x, rh0);
      rh1 = fmaf(u3r[c], xv.y, rh1);
      rh2 = fmaf(u3r[c], xv.z, rh2);
      rh3 = fmaf(u3r[c], xv.w, rh3);
      a1[c][0] = fmaf(w1, xv.x, a1[c][0]);
      a1[c][1] = fmaf(w1, xv.y, a1[c][1]);
      a1[c][2] = fmaf(w1, xv.z, a1[c][2]);
      a1[c][3] = fmaf(w1, xv.w, a1[c][3]);
    }
#pragma unroll
    for (int c = 0; c < C_; ++c) {
      const float w2 = u2[c * N_ + n];
      a2[c][0] = fmaf(w2, rh0, a2[c][0]);
      a2[c][1] = fmaf(w2, rh1, a2[c][1]);
      a2[c][2] = fmaf(w2, rh2, a2[c][2]);
      a2[c][3] = fmaf(w2, rh3, a2[c][3]);
    }
  }

  // cross-wave (sub) reduction via LDS, then atomicAdd per element
  __shared__ float red[4][C_ * T_];  // 32 KB
  float* dst1 = x_u1 + b * (C_ * T_);
  float* dst2 = r2 + b * (C_ * T_);

#pragma unroll
  for (int c = 0; c < C_; ++c)
#pragma unroll
    for (int q = 0; q < 4; ++q) red[sub][c * T_ + t0 + q] = a1[c][q];
  __syncthreads();
  for (int e = tid; e < C_ * T_; e += 256)
    atomicAdd(dst1 + e, red[0][e] + red[1][e] + red[2][e] + red[3][e]);
  __syncthreads();

#pragma unroll
  for (int c = 0; c < C_; ++c)
#pragma unroll
    for (int q = 0; q < 4; ++q) red[sub][c * T_ + t0 + q] = a2[c][q];
  __syncthreads();
  for (int e = tid; e < C_ * T_; e += 256)
    atomicAdd(dst2 + e, red[0][e] + red[1][e] + red[2][e] + red[3][e]);
}

// ---------------------------------------------------------------------------
// Pass 2: S[b,t,s] = sigmoid( sum_c x_u1[b,t,c]*R2[b,c,s] + bias[t,s] )
// grid = B*T = 2048 blocks, thread = s
// ---------------------------------------------------------------------------
__global__ __launch_bounds__(256) void prodsig(
    const float* __restrict__ x_u1, const float* __restrict__ r2,
    const float* __restrict__ bias, float* __restrict__ S) {
  const int b = blockIdx.x >> 8;
  const int t = blockIdx.x & 255;
  const int j = threadIdx.x;
  float acc = bias[t * T_ + j];
#pragma unroll
  for (int c = 0; c < C_; ++c)
    acc = fmaf(x_u1[b * 2048 + c * T_ + t], r2[b * 2048 + c * T_ + j], acc);
  S[(size_t)blockIdx.x * T_ + j] = 1.f / (1.f + expf(-acc));
}

// ---------------------------------------------------------------------------
// Pass 3: E[b,i,j] = sum_k v[i,k] * S[b,k,j], then stable softmax over j.
// Block handles 8 rows (i) for one b; thread owns column j.
// grid = B * 32 = 256 blocks
// ---------------------------------------------------------------------------
__global__ __launch_bounds__(256) void esoftmax(
    const float* __restrict__ v, const float* __restrict__ S,
    float* __restrict__ out) {
  __shared__ float vlds[8][T_];  // 8 KB: v rows for this tile
  __shared__ float elds[8][T_];  // 8 KB: E tile
  __shared__ float rmax[8], rinv[8];
  const int b = blockIdx.x >> 5;
  const int i0 = (blockIdx.x & 31) << 3;
  const int j = threadIdx.x;

#pragma unroll
  for (int r = 0; r < 8; ++r) vlds[r][j] = v[(i0 + r) * T_ + j];
  __syncthreads();

  float acc[8] = {0.f, 0.f, 0.f, 0.f, 0.f, 0.f, 0.f, 0.f};
  const float* Sb = S + (size_t)b * T_ * T_;
  for (int k = 0; k < T_; k += 4) {
    const float s0 = Sb[(k + 0) * T_ + j];
    const float s1 = Sb[(k + 1) * T_ + j];
    const float s2 = Sb[(k + 2) * T_ + j];
    const float s3 = Sb[(k + 3) * T_ + j];
#pragma unroll
    for (int r = 0; r < 8; ++r) {
      const float4 vv = *(const float4*)&vlds[r][k];  // LDS broadcast
      acc[r] = fmaf(vv.x, s0,
               fmaf(vv.y, s1, fmaf(vv.z, s2, fmaf(vv.w, s3, acc[r]))));
    }
  }

#pragma unroll
  for (int r = 0; r < 8; ++r) elds[r][j] = acc[r];
  __syncthreads();

  const int wave = j >> 6, lane = j & 63;
  for (int r = wave; r < 8; r += 4) {
    float m = -INFINITY;
#pragma unroll
    for (int q = 0; q < 4; ++q) m = fmaxf(m, elds[r][lane + q * 64]);
#pragma unroll
    for (int off = 32; off > 0; off >>= 1) m = fmaxf(m, __shfl_xor(m, off, 64));
    float sm = 0.f;
#pragma unroll
    for (int q = 0; q < 4; ++q) sm += expf(elds[r][lane + q * 64] - m);
#pragma unroll
    for (int off = 32; off > 0; off >>= 1) sm += __shfl_xor(sm, off, 64);
    if (lane == 0) { rmax[r] = m; rinv[r] = 1.f / sm; }
  }
  __syncthreads();

  float* ob = out + ((size_t)b * T_ + i0) * T_;
#pragma unroll
  for (int r = 0; r < 8; ++r)
    ob[r * T_ + j] = expf(elds[r][j] - rmax[r]) * rinv[r];
}

// ---------------------------------------------------------------------------
extern "C" void kernel_launch(void* const* d_in, const int* in_sizes, int n_in,
                              void* d_out, int out_size, void* d_ws, size_t ws_size,
                              hipStream_t stream) {
  const float* x    = (const float*)d_in[0];
  const float* u1   = (const float*)d_in[1];
  const float* u2   = (const float*)d_in[2];
  const float* u3   = (const float*)d_in[3];
  const float* bias = (const float*)d_in[4];
  const float* v    = (const float*)d_in[5];
  float* out = (float*)d_out;

  char* ws = (char*)d_ws;
  float* x_u1 = (float*)(ws);                      // 64 KB
  float* r2   = (float*)(ws + (64u << 10));        // 64 KB
  float* S    = (float*)(ws + (128u << 10));       // 2 MB

  // zero the atomic-accumulated outputs (ws is poisoned each call)
  hipMemsetAsync(x_u1, 0, 128u << 10, stream);

  pass1<<<B_ * CHUNKS, 256, 0, stream>>>(x, u1, u2, u3, x_u1, r2);
  prodsig<<<B_ * T_, 256, 0, stream>>>(x_u1, r2, bias, S);
  esoftmax<<<B_ * (T_ / 8), 256, 0, stream>>>(v, S, out);
}